// Round 7
// baseline (1061.128 us; speedup 1.0000x reference)
//
#include <hip/hip_runtime.h>
#include <hip/hip_bf16.h>

#define F 128
#define F3 384
#define NRBF 20
#define NITER 3
#define KP 24   // padded filter K: 0..19 phi*fc, 20 fc (bias slot), 21..23 zero

typedef __hip_bfloat16 bf16;
typedef __bf16 bfrag __attribute__((ext_vector_type(8)));
typedef float f32x4 __attribute__((ext_vector_type(4)));

__device__ __forceinline__ float b2f(bf16 v) { return __bfloat162float(v); }
__device__ __forceinline__ bf16 f2b(float v) { return __float2bfloat16(v); }
__device__ __forceinline__ bfrag ldb(const bf16* p) { return *(const bfrag*)p; }
__device__ __forceinline__ bfrag ldsb(const __bf16* p) { return *(const bfrag*)p; }
__device__ __forceinline__ bfrag cvtf(const float* p) {
    bfrag r;
#pragma unroll
    for (int j = 0; j < 8; ++j) r[j] = (__bf16)p[j];
    return r;
}

// ---------------- dtype detection: bf16 (flag=0) vs f32 (flag=1) ----------------
__global__ void detect_kernel(const unsigned short* __restrict__ raw, int n_u16,
                              int* __restrict__ flag) {
    int i = blockIdx.x * blockDim.x + threadIdx.x;
    int bad = 0;
    for (int k = i; k < n_u16; k += blockDim.x * gridDim.x) {
        unsigned e = (raw[k] >> 7) & 0xFFu;
        if (e >= 140u) bad = 1;
    }
    if (bad) atomicOr(flag, 1);
}

// ---------------- fused param convert: 13 arrays in one launch ----------------
struct CvtArgs {
    const void* src[13];
    float* dst[13];
    int end[14];   // end[0]=0, end[s+1]=cumulative element count
};
__global__ void cvt_all_kernel(CvtArgs a, const int* __restrict__ flag, int total) {
    int idx = blockIdx.x * blockDim.x + threadIdx.x;
    if (idx >= total) return;
    int s = 0;
    while (idx >= a.end[s + 1]) ++s;
    int local = idx - a.end[s];
    float v = (*flag) ? ((const float*)a.src[s])[local]
                      : b2f(((const bf16*)a.src[s])[local]);
    a.dst[s][local] = v;
}

// ---------------- fused transpose: 5 weight tensors, f32[NITER][K][Nn]->bf16[NITER][Nn][K] ----
struct TpArgs {
    const float* src[5];
    bf16* dst[5];
    int K[5];
    int Nn[5];
    int end[6];
};
__global__ void tpose_all_kernel(TpArgs a, int total) {
    int idx = blockIdx.x * blockDim.x + threadIdx.x;
    if (idx >= total) return;
    int s = 0;
    while (idx >= a.end[s + 1]) ++s;
    int local = idx - a.end[s];
    int K = a.K[s], Nn = a.Nn[s], slice = K * Nn;
    int t = local / slice, j = local - t * slice;
    int n = j / K, k = j - n * K;
    a.dst[s][local] = f2b(a.src[s][t * slice + k * Nn + n]);
}

// ---------------- fWTf: f32 [NITER][384][24], k=0..19 fW, k=20 fb, rest 0 ----------------
__global__ void fwt_kernel(const float* __restrict__ fW, const float* __restrict__ fb,
                           float* __restrict__ dst, int total) {
    int idx = blockIdx.x * blockDim.x + threadIdx.x;
    if (idx >= total) return;
    int k = idx % KP, rest = idx / KP;
    int n = rest % F3, t = rest / F3;
    float v = (k < NRBF) ? fW[k * (F3 * NITER) + t * F3 + n]
                         : (k == NRBF ? fb[t * F3 + n] : 0.0f);
    dst[idx] = v;
}

// ---------------- geometry -> CSR-slot-ordered edge data ----------------
__global__ void geom_kernel(const float* __restrict__ pos, const int* __restrict__ ii,
                            const int* __restrict__ jj, const int* __restrict__ rank,
                            float* __restrict__ phifc2, float* __restrict__ dir2,
                            int* __restrict__ jj2, int E) {
    int e = blockIdx.x * blockDim.x + threadIdx.x;
    if (e >= E) return;
    int i = ii[e], j = jj[e], l = rank[e];
    float r[3];
#pragma unroll
    for (int d = 0; d < 3; ++d) {
        float v = pos[j * 3 + d] - pos[i * 3 + d];
        if (fabsf(v) < 1e-6f) v = 1e-6f;
        r[d] = v;
    }
    float dd = sqrtf(r[0] * r[0] + r[1] * r[1] + r[2] * r[2]);
    float inv = 1.0f / dd;
    jj2[l] = j;
#pragma unroll
    for (int d = 0; d < 3; ++d) dir2[(size_t)l * 4 + d] = r[d] * inv;
    dir2[(size_t)l * 4 + 3] = 0.0f;
    const float CUT = 5.0f;
    const float PI = 3.14159265358979323846f;
    float fc = (dd < CUT) ? 0.5f * (cosf(PI * dd / CUT) + 1.0f) : 0.0f;
    const float width = CUT / (NRBF - 1);
    const float coeff = -0.5f / (width * width);
    float* pr = phifc2 + (size_t)l * KP;
#pragma unroll
    for (int k = 0; k < NRBF; ++k) {
        float diff = dd - (float)k * width;
        pr[k] = expf(coeff * diff * diff) * fc;
    }
    pr[NRBF] = fc;
    pr[NRBF + 1] = 0.0f;
    pr[NRBF + 2] = 0.0f;
    pr[NRBF + 3] = 0.0f;
}

// ---------------- initial q from embedding ----------------
__global__ void embed_kernel(const int* __restrict__ z, const float* __restrict__ emb,
                             float* __restrict__ q, int N) {
    int idx = blockIdx.x * blockDim.x + threadIdx.x;
    if (idx >= N * F) return;
    int n = idx >> 7, f = idx & 127;
    q[idx] = emb[z[n] * F + f];
}

// ---------------- CSR build ----------------
__global__ void count_kernel(const int* __restrict__ ii, int* __restrict__ counts, int E) {
    int e = blockIdx.x * blockDim.x + threadIdx.x;
    if (e < E) atomicAdd(&counts[ii[e]], 1);
}

__global__ void scan_kernel(const int* __restrict__ counts, int* __restrict__ offs, int N) {
    __shared__ int cum[1024];
    int t = threadIdx.x;
    int chunk = (N + 1023) >> 10;
    int b = t * chunk;
    int e = b + chunk; if (e > N) e = N;
    int s = 0;
    for (int a = b; a < e; ++a) s += counts[a];
    cum[t] = s;
    __syncthreads();
    for (int o = 1; o < 1024; o <<= 1) {
        int u = (t >= o) ? cum[t - o] : 0;
        __syncthreads();
        cum[t] += u;
        __syncthreads();
    }
    int run = cum[t] - s;
    for (int a = b; a < e; ++a) { offs[a] = run; run += counts[a]; }
    if (t == 1023) offs[N] = cum[1023];
}

__global__ void fill_kernel(const int* __restrict__ ii, const int* __restrict__ offs,
                            int* __restrict__ cursor, int* __restrict__ rank, int E) {
    int e = blockIdx.x * blockDim.x + threadIdx.x;
    if (e >= E) return;
    int i = ii[e];
    int p = atomicAdd(&cursor[i], 1);
    rank[e] = offs[i] + p;
}

// ---------------- atom_x via MFMA: X = silu(Q@W1+b1)@W2+b2, 32 atoms/block ----------------
__global__ __launch_bounds__(256) void atom_x_mfma(
    const float* __restrict__ q, const bf16* __restrict__ W1T, const float* __restrict__ b1,
    const bf16* __restrict__ W2T, const float* __restrict__ b2, bf16* __restrict__ x, int N) {
    __shared__ __bf16 H[32][136];
    int tid = threadIdx.x;
    int w = tid >> 6, l = tid & 63;
    int lm = l & 15, q4 = l >> 4;
    int i0 = blockIdx.x * 32;
    f32x4 acc[2][2] = {};
    int r0 = min(i0 + lm, N - 1);
    int r1 = min(i0 + 16 + lm, N - 1);
    for (int kt = 0; kt < 4; ++kt) {
        int ko = kt * 32 + q4 * 8;
        bfrag a0 = cvtf(q + (size_t)r0 * F + ko);
        bfrag a1 = cvtf(q + (size_t)r1 * F + ko);
        bfrag b0 = ldb(W1T + (size_t)(w * 32 + lm) * F + ko);
        bfrag b1f = ldb(W1T + (size_t)(w * 32 + 16 + lm) * F + ko);
        acc[0][0] = __builtin_amdgcn_mfma_f32_16x16x32_bf16(a0, b0, acc[0][0], 0, 0, 0);
        acc[1][0] = __builtin_amdgcn_mfma_f32_16x16x32_bf16(a1, b0, acc[1][0], 0, 0, 0);
        acc[0][1] = __builtin_amdgcn_mfma_f32_16x16x32_bf16(a0, b1f, acc[0][1], 0, 0, 0);
        acc[1][1] = __builtin_amdgcn_mfma_f32_16x16x32_bf16(a1, b1f, acc[1][1], 0, 0, 0);
    }
#pragma unroll
    for (int nt = 0; nt < 2; ++nt) {
        int col = w * 32 + nt * 16 + lm;
        float bb = b1[col];
#pragma unroll
        for (int mt = 0; mt < 2; ++mt)
#pragma unroll
            for (int r = 0; r < 4; ++r) {
                float v = acc[mt][nt][r] + bb;
                H[mt * 16 + q4 * 4 + r][col] = (__bf16)(v / (1.0f + expf(-v)));
            }
    }
    __syncthreads();
#pragma unroll
    for (int j = 0; j < 6; ++j) {
        int n0 = w * 96 + j * 16;
        f32x4 c0 = {}, c1 = {};
        const bf16* bp = W2T + (size_t)(n0 + lm) * F;
        for (int kt = 0; kt < 4; ++kt) {
            int ko = kt * 32 + q4 * 8;
            bfrag a0 = ldsb(&H[lm][ko]);
            bfrag a1 = ldsb(&H[16 + lm][ko]);
            bfrag bf = ldb(bp + ko);
            c0 = __builtin_amdgcn_mfma_f32_16x16x32_bf16(a0, bf, c0, 0, 0, 0);
            c1 = __builtin_amdgcn_mfma_f32_16x16x32_bf16(a1, bf, c1, 0, 0, 0);
        }
        int col = n0 + lm;
        float bb = b2[col];
#pragma unroll
        for (int r = 0; r < 4; ++r) {
            int row0 = i0 + q4 * 4 + r;
            int row1 = row0 + 16;
            if (row0 < N) x[(size_t)row0 * F3 + col] = f2b(c0[r] + bb);
            if (row1 < N) x[(size_t)row1 * F3 + col] = f2b(c1[r] + bb);
        }
    }
}

// ---------------- edge gather: 1 block/atom, 384 threads, class-split filter ----------------
// Thread (c,f) owns filter column c*128+f: only 21 weights/thread (register-resident).
// phi rows are block-uniform -> scalar loads + SGPR-operand FMA. Classes are
// wave-aligned (c = tid>>7). Class1/2 partials combined via one LDS exchange.
__global__ __launch_bounds__(384) void edge_gather_cls(
    float* __restrict__ q, const bf16* __restrict__ mu_in, const bf16* __restrict__ x,
    const float* __restrict__ phifc2, const float* __restrict__ dir2,
    const int* __restrict__ jj2, const float* __restrict__ fWTf,
    const int* __restrict__ offs, bf16* __restrict__ mu_out, int N) {
    __shared__ float Rs[3][128];
    int i = blockIdx.x;
    int tid = threadIdx.x;
    int c = tid >> 7, f = tid & 127;
    float w[NRBF + 1];
    {
        const float* wp = fWTf + (size_t)(c * 128 + f) * KP;
#pragma unroll
        for (int k = 0; k <= NRBF; ++k) w[k] = wp[k];
    }
    int beg = offs[i], end = offs[i + 1];
    float a0 = 0.0f, a1 = 0.0f, a2 = 0.0f;
    for (int l = beg; l < end; ++l) {
        const float* pr = phifc2 + (size_t)l * KP;
        float fv = 0.0f;
#pragma unroll
        for (int k = 0; k <= NRBF; ++k) fv += pr[k] * w[k];
        int j = jj2[l];
        float xv = b2f(x[(size_t)j * F3 + c * 128 + f]);
        float g = fv * xv;
        if (c == 0) {
            a0 += g;
        } else if (c == 1) {
            a0 += g * dir2[(size_t)l * 4 + 0];
            a1 += g * dir2[(size_t)l * 4 + 1];
            a2 += g * dir2[(size_t)l * 4 + 2];
        } else {
            const bf16* mj = mu_in + (size_t)j * F3 + f;
            a0 += g * b2f(mj[0]);
            a1 += g * b2f(mj[128]);
            a2 += g * b2f(mj[256]);
        }
    }
    if (c == 1) { Rs[0][f] = a0; Rs[1][f] = a1; Rs[2][f] = a2; }
    __syncthreads();
    if (c == 0) {
        q[(size_t)i * F + f] += a0;
    } else if (c == 2) {
        size_t mb = (size_t)i * F3 + f;
        mu_out[mb]       = f2b(b2f(mu_in[mb])       + a0 + Rs[0][f]);
        mu_out[mb + 128] = f2b(b2f(mu_in[mb + 128]) + a1 + Rs[1][f]);
        mu_out[mb + 256] = f2b(b2f(mu_in[mb + 256]) + a2 + Rs[2][f]);
    }
}

// ---------------- mixing via MFMA, 16 atoms/block ----------------
__global__ __launch_bounds__(256) void mix_mfma(
    float* __restrict__ q, bf16* __restrict__ mu,
    const bf16* __restrict__ WmixT, const bf16* __restrict__ W1T, const float* __restrict__ b1,
    const bf16* __restrict__ W2T, const float* __restrict__ b2, int N) {
    __shared__ __bf16 MM[48][264];
    __shared__ __bf16 CT[16][264];
    __shared__ __bf16 HM[16][136];
    __shared__ __bf16 Y[16][392];
    int tid = threadIdx.x;
    int w = tid >> 6, l = tid & 63;
    int lm = l & 15, q4 = l >> 4;
    int i0 = blockIdx.x * 16;
    int rowsM = N * 3;
    {
        f32x4 acc[3][4] = {};
        int mr[3];
#pragma unroll
        for (int mt = 0; mt < 3; ++mt) mr[mt] = min(i0 * 3 + mt * 16 + lm, rowsM - 1);
        for (int kt = 0; kt < 4; ++kt) {
            int ko = kt * 32 + q4 * 8;
            bfrag a[3], b[4];
#pragma unroll
            for (int mt = 0; mt < 3; ++mt) a[mt] = ldb(mu + (size_t)mr[mt] * F + ko);
#pragma unroll
            for (int nt = 0; nt < 4; ++nt)
                b[nt] = ldb(WmixT + (size_t)(w * 64 + nt * 16 + lm) * F + ko);
#pragma unroll
            for (int mt = 0; mt < 3; ++mt)
#pragma unroll
                for (int nt = 0; nt < 4; ++nt)
                    acc[mt][nt] = __builtin_amdgcn_mfma_f32_16x16x32_bf16(a[mt], b[nt], acc[mt][nt], 0, 0, 0);
        }
#pragma unroll
        for (int mt = 0; mt < 3; ++mt)
#pragma unroll
            for (int nt = 0; nt < 4; ++nt)
#pragma unroll
                for (int r = 0; r < 4; ++r)
                    MM[mt * 16 + q4 * 4 + r][w * 64 + nt * 16 + lm] = (__bf16)acc[mt][nt][r];
    }
    __syncthreads();
    for (int idx = tid; idx < 16 * F; idx += 256) {
        int a = idx >> 7, f = idx & 127;
        int i = min(i0 + a, N - 1);
        float v0 = (float)MM[a * 3 + 0][f];
        float v1 = (float)MM[a * 3 + 1][f];
        float v2 = (float)MM[a * 3 + 2][f];
        CT[a][f] = (__bf16)q[(size_t)i * F + f];
        CT[a][F + f] = (__bf16)sqrtf(v0 * v0 + v1 * v1 + v2 * v2 + 1e-8f);
    }
    __syncthreads();
    {
        f32x4 c[2] = {};
        for (int kt = 0; kt < 8; ++kt) {
            int ko = kt * 32 + q4 * 8;
            bfrag a = ldsb(&CT[lm][ko]);
#pragma unroll
            for (int nt = 0; nt < 2; ++nt) {
                bfrag b = ldb(W1T + (size_t)(w * 32 + nt * 16 + lm) * 256 + ko);
                c[nt] = __builtin_amdgcn_mfma_f32_16x16x32_bf16(a, b, c[nt], 0, 0, 0);
            }
        }
#pragma unroll
        for (int nt = 0; nt < 2; ++nt) {
            int col = w * 32 + nt * 16 + lm;
            float bb = b1[col];
#pragma unroll
            for (int r = 0; r < 4; ++r) {
                float v = c[nt][r] + bb;
                HM[q4 * 4 + r][col] = (__bf16)(v / (1.0f + expf(-v)));
            }
        }
    }
    __syncthreads();
#pragma unroll
    for (int j = 0; j < 6; ++j) {
        int n0 = w * 96 + j * 16;
        f32x4 c = {};
        const bf16* bp = W2T + (size_t)(n0 + lm) * F;
        for (int kt = 0; kt < 4; ++kt) {
            int ko = kt * 32 + q4 * 8;
            bfrag a = ldsb(&HM[lm][ko]);
            bfrag b = ldb(bp + ko);
            c = __builtin_amdgcn_mfma_f32_16x16x32_bf16(a, b, c, 0, 0, 0);
        }
        int col = n0 + lm;
        float bb = b2[col];
#pragma unroll
        for (int r = 0; r < 4; ++r)
            Y[q4 * 4 + r][col] = (__bf16)(c[r] + bb);
    }
    __syncthreads();
    for (int idx = tid; idx < 16 * F; idx += 256) {
        int a = idx >> 7, f = idx & 127;
        int i = i0 + a;
        if (i >= N) continue;
        float V0 = (float)MM[a * 3 + 0][f], W0 = (float)MM[a * 3 + 0][F + f];
        float V1 = (float)MM[a * 3 + 1][f], W1v = (float)MM[a * 3 + 1][F + f];
        float V2 = (float)MM[a * 3 + 2][f], W2v = (float)MM[a * 3 + 2][F + f];
        float s = V0 * W0 + V1 * W1v + V2 * W2v;
        float yq = (float)Y[a][f], ym = (float)Y[a][F + f], ys = (float)Y[a][2 * F + f];
        q[(size_t)i * F + f] += yq + ys * s;
        size_t mb = (size_t)i * F3 + f;
        mu[mb]       = f2b(b2f(mu[mb]) + ym * W0);
        mu[mb + 128] = f2b(b2f(mu[mb + 128]) + ym * W1v);
        mu[mb + 256] = f2b(b2f(mu[mb + 256]) + ym * W2v);
    }
}

// ---------------- output: q ‖ mu, dtype per flag ----------------
__global__ void out_kernel(const float* __restrict__ q, const bf16* __restrict__ mu,
                           void* __restrict__ out, int N, const int* __restrict__ flag) {
    int idx = blockIdx.x * blockDim.x + threadIdx.x;
    int nq = N * F;
    int tot = nq + N * F3;
    if (idx >= tot) return;
    float v = (idx < nq) ? q[idx] : b2f(mu[idx - nq]);
    if (*flag) ((float*)out)[idx] = v;
    else       ((bf16*)out)[idx] = f2b(v);
}

extern "C" void kernel_launch(void* const* d_in, const int* in_sizes, int n_in,
                              void* d_out, int out_size, void* d_ws, size_t ws_size,
                              hipStream_t stream) {
    const int* z = (const int*)d_in[0];
    const int* idx_i = (const int*)d_in[2];
    const int* idx_j = (const int*)d_in[3];

    int N = in_sizes[0];
    int E = in_sizes[2];

    char* base = (char*)d_ws;
    size_t off = 0;
    auto alloc = [&](size_t bytes) -> void* {
        void* p = base + off;
        off += (bytes + 255) & ~(size_t)255;
        return p;
    };

    int* flag = (int*)alloc(4);
    float* pos_f = (float*)alloc((size_t)in_sizes[1] * 4);
    float* emb_f = (float*)alloc((size_t)in_sizes[4] * 4);
    float* fW_f = (float*)alloc((size_t)in_sizes[5] * 4);
    float* fb_f = (float*)alloc((size_t)in_sizes[6] * 4);
    float* iW1_f = (float*)alloc((size_t)in_sizes[7] * 4);
    float* ib1_f = (float*)alloc((size_t)in_sizes[8] * 4);
    float* iW2_f = (float*)alloc((size_t)in_sizes[9] * 4);
    float* ib2_f = (float*)alloc((size_t)in_sizes[10] * 4);
    float* mWmix_f = (float*)alloc((size_t)in_sizes[11] * 4);
    float* mW1_f = (float*)alloc((size_t)in_sizes[12] * 4);
    float* mb1_f = (float*)alloc((size_t)in_sizes[13] * 4);
    float* mW2_f = (float*)alloc((size_t)in_sizes[14] * 4);
    float* mb2_f = (float*)alloc((size_t)in_sizes[15] * 4);
    bf16* iW1T = (bf16*)alloc((size_t)NITER * F * F * 2);
    bf16* iW2T = (bf16*)alloc((size_t)NITER * F3 * F * 2);
    bf16* mWmixT = (bf16*)alloc((size_t)NITER * 2 * F * F * 2);
    bf16* mW1T = (bf16*)alloc((size_t)NITER * F * 2 * F * 2);
    bf16* mW2T = (bf16*)alloc((size_t)NITER * F3 * F * 2);
    float* fWTf = (float*)alloc((size_t)NITER * F3 * KP * 4);
    float* q = (float*)alloc((size_t)N * F * 4);
    bf16* mua = (bf16*)alloc((size_t)N * F3 * 2);
    bf16* mub = (bf16*)alloc((size_t)N * F3 * 2);
    bf16* xbuf = (bf16*)alloc((size_t)N * F3 * 2);
    float* phifc2 = (float*)alloc((size_t)(E + 16) * KP * 4);
    float* dir2 = (float*)alloc((size_t)(E + 16) * 4 * 4);
    int* jj2 = (int*)alloc((size_t)(E + 16) * 4);
    int* rank = (int*)alloc((size_t)E * 4);
    int* counts = (int*)alloc((size_t)N * 4);
    int* offs = (int*)alloc((size_t)(N + 1) * 4);

    hipMemsetAsync(flag, 0, 4, stream);
    detect_kernel<<<64, 256, 0, stream>>>((const unsigned short*)d_in[1], in_sizes[1], flag);

    // fused parameter conversion (13 arrays, 1 launch)
    {
        CvtArgs a;
        const int srcIdx[13] = {1, 4, 5, 6, 7, 8, 9, 10, 11, 12, 13, 14, 15};
        float* dsts[13] = {pos_f, emb_f, fW_f, fb_f, iW1_f, ib1_f, iW2_f, ib2_f,
                           mWmix_f, mW1_f, mb1_f, mW2_f, mb2_f};
        int cum = 0;
        a.end[0] = 0;
        for (int s = 0; s < 13; ++s) {
            a.src[s] = d_in[srcIdx[s]];
            a.dst[s] = dsts[s];
            cum += in_sizes[srcIdx[s]];
            a.end[s + 1] = cum;
        }
        cvt_all_kernel<<<(cum + 255) / 256, 256, 0, stream>>>(a, flag, cum);
    }

    // fused weight transposes (5 tensors, 1 launch)
    {
        TpArgs a;
        const float* srcs[5] = {iW1_f, iW2_f, mWmix_f, mW1_f, mW2_f};
        bf16* dsts[5] = {iW1T, iW2T, mWmixT, mW1T, mW2T};
        int Ks[5] = {F, F, F, 2 * F, F};
        int Nns[5] = {F, F3, 2 * F, F, F3};
        int cum = 0;
        a.end[0] = 0;
        for (int s = 0; s < 5; ++s) {
            a.src[s] = srcs[s];
            a.dst[s] = dsts[s];
            a.K[s] = Ks[s];
            a.Nn[s] = Nns[s];
            cum += NITER * Ks[s] * Nns[s];
            a.end[s + 1] = cum;
        }
        tpose_all_kernel<<<(cum + 255) / 256, 256, 0, stream>>>(a, cum);
    }
    {
        int total = NITER * F3 * KP;
        fwt_kernel<<<(total + 255) / 256, 256, 0, stream>>>(fW_f, fb_f, fWTf, total);
    }

    // CSR build (rank needed by geom)
    hipMemsetAsync(counts, 0, (size_t)N * 4, stream);
    count_kernel<<<(E + 255) / 256, 256, 0, stream>>>(idx_i, counts, E);
    scan_kernel<<<1, 1024, 0, stream>>>(counts, offs, N);
    hipMemsetAsync(counts, 0, (size_t)N * 4, stream);
    fill_kernel<<<(E + 255) / 256, 256, 0, stream>>>(idx_i, offs, counts, rank, E);

    geom_kernel<<<(E + 255) / 256, 256, 0, stream>>>(pos_f, idx_i, idx_j, rank,
                                                     phifc2, dir2, jj2, E);
    embed_kernel<<<(N * F + 255) / 256, 256, 0, stream>>>(z, emb_f, q, N);
    hipMemsetAsync(mua, 0, (size_t)N * F3 * 2, stream);

    bf16* muin = mua;
    bf16* muout = mub;
    for (int t = 0; t < NITER; ++t) {
        atom_x_mfma<<<(N + 31) / 32, 256, 0, stream>>>(q, iW1T + (size_t)t * F * F, ib1_f + t * F,
                                                       iW2T + (size_t)t * F3 * F, ib2_f + t * F3,
                                                       xbuf, N);
        edge_gather_cls<<<N, 384, 0, stream>>>(q, muin, xbuf, phifc2, dir2, jj2,
                                               fWTf + (size_t)t * F3 * KP, offs, muout, N);
        mix_mfma<<<(N + 15) / 16, 256, 0, stream>>>(q, muout, mWmixT + (size_t)t * 2 * F * F,
                                                    mW1T + (size_t)t * F * 2 * F, mb1_f + t * F,
                                                    mW2T + (size_t)t * F3 * F, mb2_f + t * F3, N);
        bf16* tm = muin; muin = muout; muout = tm;
    }

    int tot = N * (F + F3);
    out_kernel<<<(tot + 255) / 256, 256, 0, stream>>>(q, muin, d_out, N, flag);
}

// Round 8
// 824.280 us; speedup vs baseline: 1.2873x; 1.2873x over previous
//
#include <hip/hip_runtime.h>
#include <hip/hip_bf16.h>

#define F 128
#define F3 384
#define NRBF 20
#define NITER 3
#define KP 24   // padded filter K: 0..19 phi*fc, 20 fc (bias slot), 21..23 zero

typedef __hip_bfloat16 bf16;
typedef __bf16 bfrag __attribute__((ext_vector_type(8)));
typedef float f32x4 __attribute__((ext_vector_type(4)));

__device__ __forceinline__ float b2f(bf16 v) { return __bfloat162float(v); }
__device__ __forceinline__ bf16 f2b(float v) { return __float2bfloat16(v); }
__device__ __forceinline__ bfrag ldb(const bf16* p) { return *(const bfrag*)p; }
__device__ __forceinline__ bfrag ldsb(const __bf16* p) { return *(const bfrag*)p; }
__device__ __forceinline__ bfrag cvtf(const float* p) {
    bfrag r;
#pragma unroll
    for (int j = 0; j < 8; ++j) r[j] = (__bf16)p[j];
    return r;
}

// ---------------- dtype detection: bf16 (flag=0) vs f32 (flag=1) ----------------
__global__ void detect_kernel(const unsigned short* __restrict__ raw, int n_u16,
                              int* __restrict__ flag) {
    int i = blockIdx.x * blockDim.x + threadIdx.x;
    int bad = 0;
    for (int k = i; k < n_u16; k += blockDim.x * gridDim.x) {
        unsigned e = (raw[k] >> 7) & 0xFFu;
        if (e >= 140u) bad = 1;
    }
    if (bad) atomicOr(flag, 1);
}

// ---------------- fused param convert: 13 arrays in one launch ----------------
struct CvtArgs {
    const void* src[13];
    float* dst[13];
    int end[14];
};
__global__ void cvt_all_kernel(CvtArgs a, const int* __restrict__ flag, int total) {
    int idx = blockIdx.x * blockDim.x + threadIdx.x;
    if (idx >= total) return;
    int s = 0;
    while (idx >= a.end[s + 1]) ++s;
    int local = idx - a.end[s];
    float v = (*flag) ? ((const float*)a.src[s])[local]
                      : b2f(((const bf16*)a.src[s])[local]);
    a.dst[s][local] = v;
}

// ---------------- fused transpose: 5 weight tensors, f32[NITER][K][Nn]->bf16[NITER][Nn][K] ----
struct TpArgs {
    const float* src[5];
    bf16* dst[5];
    int K[5];
    int Nn[5];
    int end[6];
};
__global__ void tpose_all_kernel(TpArgs a, int total) {
    int idx = blockIdx.x * blockDim.x + threadIdx.x;
    if (idx >= total) return;
    int s = 0;
    while (idx >= a.end[s + 1]) ++s;
    int local = idx - a.end[s];
    int K = a.K[s], Nn = a.Nn[s], slice = K * Nn;
    int t = local / slice, j = local - t * slice;
    int n = j / K, k = j - n * K;
    a.dst[s][local] = f2b(a.src[s][t * slice + k * Nn + n]);
}

// ---------------- fWTf: f32 [NITER][384][24], k=0..19 fW, k=20 fb, rest 0 ----------------
__global__ void fwt_kernel(const float* __restrict__ fW, const float* __restrict__ fb,
                           float* __restrict__ dst, int total) {
    int idx = blockIdx.x * blockDim.x + threadIdx.x;
    if (idx >= total) return;
    int k = idx % KP, rest = idx / KP;
    int n = rest % F3, t = rest / F3;
    float v = (k < NRBF) ? fW[k * (F3 * NITER) + t * F3 + n]
                         : (k == NRBF ? fb[t * F3 + n] : 0.0f);
    dst[idx] = v;
}

// ---------------- geometry -> CSR-slot-ordered edge data ----------------
__global__ void geom_kernel(const float* __restrict__ pos, const int* __restrict__ ii,
                            const int* __restrict__ jj, const int* __restrict__ rank,
                            float* __restrict__ phifc2, float* __restrict__ dir2,
                            int* __restrict__ jj2, int E) {
    int e = blockIdx.x * blockDim.x + threadIdx.x;
    if (e >= E) return;
    int i = ii[e], j = jj[e], l = rank[e];
    float r[3];
#pragma unroll
    for (int d = 0; d < 3; ++d) {
        float v = pos[j * 3 + d] - pos[i * 3 + d];
        if (fabsf(v) < 1e-6f) v = 1e-6f;
        r[d] = v;
    }
    float dd = sqrtf(r[0] * r[0] + r[1] * r[1] + r[2] * r[2]);
    float inv = 1.0f / dd;
    jj2[l] = j;
#pragma unroll
    for (int d = 0; d < 3; ++d) dir2[(size_t)l * 4 + d] = r[d] * inv;
    dir2[(size_t)l * 4 + 3] = 0.0f;
    const float CUT = 5.0f;
    const float PI = 3.14159265358979323846f;
    float fc = (dd < CUT) ? 0.5f * (cosf(PI * dd / CUT) + 1.0f) : 0.0f;
    const float width = CUT / (NRBF - 1);
    const float coeff = -0.5f / (width * width);
    float* pr = phifc2 + (size_t)l * KP;
#pragma unroll
    for (int k = 0; k < NRBF; ++k) {
        float diff = dd - (float)k * width;
        pr[k] = expf(coeff * diff * diff) * fc;
    }
    pr[NRBF] = fc;
    pr[NRBF + 1] = 0.0f;
    pr[NRBF + 2] = 0.0f;
    pr[NRBF + 3] = 0.0f;
}

// ---------------- initial q from embedding ----------------
__global__ void embed_kernel(const int* __restrict__ z, const float* __restrict__ emb,
                             float* __restrict__ q, int N) {
    int idx = blockIdx.x * blockDim.x + threadIdx.x;
    if (idx >= N * F) return;
    int n = idx >> 7, f = idx & 127;
    q[idx] = emb[z[n] * F + f];
}

// ---------------- CSR build ----------------
__global__ void count_kernel(const int* __restrict__ ii, int* __restrict__ counts, int E) {
    int e = blockIdx.x * blockDim.x + threadIdx.x;
    if (e < E) atomicAdd(&counts[ii[e]], 1);
}

__global__ void scan_kernel(const int* __restrict__ counts, int* __restrict__ offs, int N) {
    __shared__ int cum[1024];
    int t = threadIdx.x;
    int chunk = (N + 1023) >> 10;
    int b = t * chunk;
    int e = b + chunk; if (e > N) e = N;
    int s = 0;
    for (int a = b; a < e; ++a) s += counts[a];
    cum[t] = s;
    __syncthreads();
    for (int o = 1; o < 1024; o <<= 1) {
        int u = (t >= o) ? cum[t - o] : 0;
        __syncthreads();
        cum[t] += u;
        __syncthreads();
    }
    int run = cum[t] - s;
    for (int a = b; a < e; ++a) { offs[a] = run; run += counts[a]; }
    if (t == 1023) offs[N] = cum[1023];
}

__global__ void fill_kernel(const int* __restrict__ ii, const int* __restrict__ offs,
                            int* __restrict__ cursor, int* __restrict__ rank, int E) {
    int e = blockIdx.x * blockDim.x + threadIdx.x;
    if (e >= E) return;
    int i = ii[e];
    int p = atomicAdd(&cursor[i], 1);
    rank[e] = offs[i] + p;
}

// ---------------- atom_x via MFMA: X = silu(Q@W1+b1)@W2+b2, 32 atoms/block ----------------
__global__ __launch_bounds__(256) void atom_x_mfma(
    const float* __restrict__ q, const bf16* __restrict__ W1T, const float* __restrict__ b1,
    const bf16* __restrict__ W2T, const float* __restrict__ b2, bf16* __restrict__ x, int N) {
    __shared__ __bf16 H[32][136];
    int tid = threadIdx.x;
    int w = tid >> 6, l = tid & 63;
    int lm = l & 15, q4 = l >> 4;
    int i0 = blockIdx.x * 32;
    f32x4 acc[2][2] = {};
    int r0 = min(i0 + lm, N - 1);
    int r1 = min(i0 + 16 + lm, N - 1);
    for (int kt = 0; kt < 4; ++kt) {
        int ko = kt * 32 + q4 * 8;
        bfrag a0 = cvtf(q + (size_t)r0 * F + ko);
        bfrag a1 = cvtf(q + (size_t)r1 * F + ko);
        bfrag b0 = ldb(W1T + (size_t)(w * 32 + lm) * F + ko);
        bfrag b1f = ldb(W1T + (size_t)(w * 32 + 16 + lm) * F + ko);
        acc[0][0] = __builtin_amdgcn_mfma_f32_16x16x32_bf16(a0, b0, acc[0][0], 0, 0, 0);
        acc[1][0] = __builtin_amdgcn_mfma_f32_16x16x32_bf16(a1, b0, acc[1][0], 0, 0, 0);
        acc[0][1] = __builtin_amdgcn_mfma_f32_16x16x32_bf16(a0, b1f, acc[0][1], 0, 0, 0);
        acc[1][1] = __builtin_amdgcn_mfma_f32_16x16x32_bf16(a1, b1f, acc[1][1], 0, 0, 0);
    }
#pragma unroll
    for (int nt = 0; nt < 2; ++nt) {
        int col = w * 32 + nt * 16 + lm;
        float bb = b1[col];
#pragma unroll
        for (int mt = 0; mt < 2; ++mt)
#pragma unroll
            for (int r = 0; r < 4; ++r) {
                float v = acc[mt][nt][r] + bb;
                H[mt * 16 + q4 * 4 + r][col] = (__bf16)(v / (1.0f + expf(-v)));
            }
    }
    __syncthreads();
#pragma unroll
    for (int j = 0; j < 6; ++j) {
        int n0 = w * 96 + j * 16;
        f32x4 c0 = {}, c1 = {};
        const bf16* bp = W2T + (size_t)(n0 + lm) * F;
        for (int kt = 0; kt < 4; ++kt) {
            int ko = kt * 32 + q4 * 8;
            bfrag a0 = ldsb(&H[lm][ko]);
            bfrag a1 = ldsb(&H[16 + lm][ko]);
            bfrag bf = ldb(bp + ko);
            c0 = __builtin_amdgcn_mfma_f32_16x16x32_bf16(a0, bf, c0, 0, 0, 0);
            c1 = __builtin_amdgcn_mfma_f32_16x16x32_bf16(a1, bf, c1, 0, 0, 0);
        }
        int col = n0 + lm;
        float bb = b2[col];
#pragma unroll
        for (int r = 0; r < 4; ++r) {
            int row0 = i0 + q4 * 4 + r;
            int row1 = row0 + 16;
            if (row0 < N) x[(size_t)row0 * F3 + col] = f2b(c0[r] + bb);
            if (row1 < N) x[(size_t)row1 * F3 + col] = f2b(c1[r] + bb);
        }
    }
}

// ---------------- edge gather: 1 block/atom, PINNED register filter weights ----------------
// R6 structure (proven 108 us) + (a) inline-asm pins forcing the 63 loop-invariant
// weights to stay in VGPRs (compiler rematerialized them in R6/R7: VGPR_Count 48/20),
// (b) phi row read as 6x dwordx4 instead of 21 scalar loads, (c) dir as 1x dwordx4.
__global__ __launch_bounds__(128, 2) void edge_gather_pin(
    float* __restrict__ q, const bf16* __restrict__ mu_in, const bf16* __restrict__ x,
    const float* __restrict__ phifc2, const float* __restrict__ dir2,
    const int* __restrict__ jj2, const float* __restrict__ fWTf,
    const int* __restrict__ offs, bf16* __restrict__ mu_out, int N) {
    int i = blockIdx.x;
    int f = threadIdx.x;
    float w0[21], w1[21], w2[21];
    {
        const f32x4* p0 = (const f32x4*)(fWTf + (size_t)f * KP);
        const f32x4* p1 = (const f32x4*)(fWTf + (size_t)(f + 128) * KP);
        const f32x4* p2 = (const f32x4*)(fWTf + (size_t)(f + 256) * KP);
#pragma unroll
        for (int k = 0; k < 6; ++k) {
            f32x4 t0 = p0[k], t1 = p1[k], t2 = p2[k];
#pragma unroll
            for (int r = 0; r < 4; ++r) {
                int kk = k * 4 + r;
                if (kk < 21) { w0[kk] = t0[r]; w1[kk] = t1[r]; w2[kk] = t2[r]; }
            }
        }
    }
    // pin: value becomes opaque to the compiler -> cannot rematerialize the load
#pragma unroll
    for (int k = 0; k < 21; ++k)
        asm volatile("" : "+v"(w0[k]), "+v"(w1[k]), "+v"(w2[k]));
    int beg = offs[i], end = offs[i + 1];
    float accq = 0.0f, am0 = 0.0f, am1 = 0.0f, am2 = 0.0f;
    for (int l = beg; l < end; ++l) {
        const f32x4* pr4 = (const f32x4*)(phifc2 + (size_t)l * KP);
        f32x4 p[6];
#pragma unroll
        for (int k = 0; k < 6; ++k) p[k] = pr4[k];
        float f0 = 0.0f, f1 = 0.0f, f2 = 0.0f;
#pragma unroll
        for (int k = 0; k < 21; ++k) {
            float ph = p[k >> 2][k & 3];
            f0 += ph * w0[k];
            f1 += ph * w1[k];
            f2 += ph * w2[k];
        }
        int j = jj2[l];
        f32x4 dv = *(const f32x4*)(dir2 + (size_t)l * 4);
        const bf16* xj = x + (size_t)j * F3;
        float dq = f0 * b2f(xj[f]);
        float dR = f1 * b2f(xj[f + 128]);
        float dM = f2 * b2f(xj[f + 256]);
        accq += dq;
        const bf16* muj = mu_in + (size_t)j * F3;
        am0 += dR * dv[0] + dM * b2f(muj[f]);
        am1 += dR * dv[1] + dM * b2f(muj[f + 128]);
        am2 += dR * dv[2] + dM * b2f(muj[f + 256]);
    }
    q[(size_t)i * F + f] += accq;
    size_t mb = (size_t)i * F3 + f;
    mu_out[mb]       = f2b(b2f(mu_in[mb]) + am0);
    mu_out[mb + 128] = f2b(b2f(mu_in[mb + 128]) + am1);
    mu_out[mb + 256] = f2b(b2f(mu_in[mb + 256]) + am2);
}

// ---------------- mixing via MFMA, 16 atoms/block ----------------
__global__ __launch_bounds__(256) void mix_mfma(
    float* __restrict__ q, bf16* __restrict__ mu,
    const bf16* __restrict__ WmixT, const bf16* __restrict__ W1T, const float* __restrict__ b1,
    const bf16* __restrict__ W2T, const float* __restrict__ b2, int N) {
    __shared__ __bf16 MM[48][264];
    __shared__ __bf16 CT[16][264];
    __shared__ __bf16 HM[16][136];
    __shared__ __bf16 Y[16][392];
    int tid = threadIdx.x;
    int w = tid >> 6, l = tid & 63;
    int lm = l & 15, q4 = l >> 4;
    int i0 = blockIdx.x * 16;
    int rowsM = N * 3;
    {
        f32x4 acc[3][4] = {};
        int mr[3];
#pragma unroll
        for (int mt = 0; mt < 3; ++mt) mr[mt] = min(i0 * 3 + mt * 16 + lm, rowsM - 1);
        for (int kt = 0; kt < 4; ++kt) {
            int ko = kt * 32 + q4 * 8;
            bfrag a[3], b[4];
#pragma unroll
            for (int mt = 0; mt < 3; ++mt) a[mt] = ldb(mu + (size_t)mr[mt] * F + ko);
#pragma unroll
            for (int nt = 0; nt < 4; ++nt)
                b[nt] = ldb(WmixT + (size_t)(w * 64 + nt * 16 + lm) * F + ko);
#pragma unroll
            for (int mt = 0; mt < 3; ++mt)
#pragma unroll
                for (int nt = 0; nt < 4; ++nt)
                    acc[mt][nt] = __builtin_amdgcn_mfma_f32_16x16x32_bf16(a[mt], b[nt], acc[mt][nt], 0, 0, 0);
        }
#pragma unroll
        for (int mt = 0; mt < 3; ++mt)
#pragma unroll
            for (int nt = 0; nt < 4; ++nt)
#pragma unroll
                for (int r = 0; r < 4; ++r)
                    MM[mt * 16 + q4 * 4 + r][w * 64 + nt * 16 + lm] = (__bf16)acc[mt][nt][r];
    }
    __syncthreads();
    for (int idx = tid; idx < 16 * F; idx += 256) {
        int a = idx >> 7, f = idx & 127;
        int i = min(i0 + a, N - 1);
        float v0 = (float)MM[a * 3 + 0][f];
        float v1 = (float)MM[a * 3 + 1][f];
        float v2 = (float)MM[a * 3 + 2][f];
        CT[a][f] = (__bf16)q[(size_t)i * F + f];
        CT[a][F + f] = (__bf16)sqrtf(v0 * v0 + v1 * v1 + v2 * v2 + 1e-8f);
    }
    __syncthreads();
    {
        f32x4 c[2] = {};
        for (int kt = 0; kt < 8; ++kt) {
            int ko = kt * 32 + q4 * 8;
            bfrag a = ldsb(&CT[lm][ko]);
#pragma unroll
            for (int nt = 0; nt < 2; ++nt) {
                bfrag b = ldb(W1T + (size_t)(w * 32 + nt * 16 + lm) * 256 + ko);
                c[nt] = __builtin_amdgcn_mfma_f32_16x16x32_bf16(a, b, c[nt], 0, 0, 0);
            }
        }
#pragma unroll
        for (int nt = 0; nt < 2; ++nt) {
            int col = w * 32 + nt * 16 + lm;
            float bb = b1[col];
#pragma unroll
            for (int r = 0; r < 4; ++r) {
                float v = c[nt][r] + bb;
                HM[q4 * 4 + r][col] = (__bf16)(v / (1.0f + expf(-v)));
            }
        }
    }
    __syncthreads();
#pragma unroll
    for (int j = 0; j < 6; ++j) {
        int n0 = w * 96 + j * 16;
        f32x4 c = {};
        const bf16* bp = W2T + (size_t)(n0 + lm) * F;
        for (int kt = 0; kt < 4; ++kt) {
            int ko = kt * 32 + q4 * 8;
            bfrag a = ldsb(&HM[lm][ko]);
            bfrag b = ldb(bp + ko);
            c = __builtin_amdgcn_mfma_f32_16x16x32_bf16(a, b, c, 0, 0, 0);
        }
        int col = n0 + lm;
        float bb = b2[col];
#pragma unroll
        for (int r = 0; r < 4; ++r)
            Y[q4 * 4 + r][col] = (__bf16)(c[r] + bb);
    }
    __syncthreads();
    for (int idx = tid; idx < 16 * F; idx += 256) {
        int a = idx >> 7, f = idx & 127;
        int i = i0 + a;
        if (i >= N) continue;
        float V0 = (float)MM[a * 3 + 0][f], W0 = (float)MM[a * 3 + 0][F + f];
        float V1 = (float)MM[a * 3 + 1][f], W1v = (float)MM[a * 3 + 1][F + f];
        float V2 = (float)MM[a * 3 + 2][f], W2v = (float)MM[a * 3 + 2][F + f];
        float s = V0 * W0 + V1 * W1v + V2 * W2v;
        float yq = (float)Y[a][f], ym = (float)Y[a][F + f], ys = (float)Y[a][2 * F + f];
        q[(size_t)i * F + f] += yq + ys * s;
        size_t mb = (size_t)i * F3 + f;
        mu[mb]       = f2b(b2f(mu[mb]) + ym * W0);
        mu[mb + 128] = f2b(b2f(mu[mb + 128]) + ym * W1v);
        mu[mb + 256] = f2b(b2f(mu[mb + 256]) + ym * W2v);
    }
}

// ---------------- output: q ‖ mu, dtype per flag ----------------
__global__ void out_kernel(const float* __restrict__ q, const bf16* __restrict__ mu,
                           void* __restrict__ out, int N, const int* __restrict__ flag) {
    int idx = blockIdx.x * blockDim.x + threadIdx.x;
    int nq = N * F;
    int tot = nq + N * F3;
    if (idx >= tot) return;
    float v = (idx < nq) ? q[idx] : b2f(mu[idx - nq]);
    if (*flag) ((float*)out)[idx] = v;
    else       ((bf16*)out)[idx] = f2b(v);
}

extern "C" void kernel_launch(void* const* d_in, const int* in_sizes, int n_in,
                              void* d_out, int out_size, void* d_ws, size_t ws_size,
                              hipStream_t stream) {
    const int* z = (const int*)d_in[0];
    const int* idx_i = (const int*)d_in[2];
    const int* idx_j = (const int*)d_in[3];

    int N = in_sizes[0];
    int E = in_sizes[2];

    char* base = (char*)d_ws;
    size_t off = 0;
    auto alloc = [&](size_t bytes) -> void* {
        void* p = base + off;
        off += (bytes + 255) & ~(size_t)255;
        return p;
    };

    int* flag = (int*)alloc(4);
    float* pos_f = (float*)alloc((size_t)in_sizes[1] * 4);
    float* emb_f = (float*)alloc((size_t)in_sizes[4] * 4);
    float* fW_f = (float*)alloc((size_t)in_sizes[5] * 4);
    float* fb_f = (float*)alloc((size_t)in_sizes[6] * 4);
    float* iW1_f = (float*)alloc((size_t)in_sizes[7] * 4);
    float* ib1_f = (float*)alloc((size_t)in_sizes[8] * 4);
    float* iW2_f = (float*)alloc((size_t)in_sizes[9] * 4);
    float* ib2_f = (float*)alloc((size_t)in_sizes[10] * 4);
    float* mWmix_f = (float*)alloc((size_t)in_sizes[11] * 4);
    float* mW1_f = (float*)alloc((size_t)in_sizes[12] * 4);
    float* mb1_f = (float*)alloc((size_t)in_sizes[13] * 4);
    float* mW2_f = (float*)alloc((size_t)in_sizes[14] * 4);
    float* mb2_f = (float*)alloc((size_t)in_sizes[15] * 4);
    bf16* iW1T = (bf16*)alloc((size_t)NITER * F * F * 2);
    bf16* iW2T = (bf16*)alloc((size_t)NITER * F3 * F * 2);
    bf16* mWmixT = (bf16*)alloc((size_t)NITER * 2 * F * F * 2);
    bf16* mW1T = (bf16*)alloc((size_t)NITER * F * 2 * F * 2);
    bf16* mW2T = (bf16*)alloc((size_t)NITER * F3 * F * 2);
    float* fWTf = (float*)alloc((size_t)NITER * F3 * KP * 4);
    float* q = (float*)alloc((size_t)N * F * 4);
    bf16* mua = (bf16*)alloc((size_t)N * F3 * 2);
    bf16* mub = (bf16*)alloc((size_t)N * F3 * 2);
    bf16* xbuf = (bf16*)alloc((size_t)N * F3 * 2);
    float* phifc2 = (float*)alloc((size_t)(E + 16) * KP * 4);
    float* dir2 = (float*)alloc((size_t)(E + 16) * 4 * 4);
    int* jj2 = (int*)alloc((size_t)(E + 16) * 4);
    int* rank = (int*)alloc((size_t)E * 4);
    int* counts = (int*)alloc((size_t)N * 4);
    int* offs = (int*)alloc((size_t)(N + 1) * 4);

    hipMemsetAsync(flag, 0, 4, stream);
    detect_kernel<<<64, 256, 0, stream>>>((const unsigned short*)d_in[1], in_sizes[1], flag);

    {
        CvtArgs a;
        const int srcIdx[13] = {1, 4, 5, 6, 7, 8, 9, 10, 11, 12, 13, 14, 15};
        float* dsts[13] = {pos_f, emb_f, fW_f, fb_f, iW1_f, ib1_f, iW2_f, ib2_f,
                           mWmix_f, mW1_f, mb1_f, mW2_f, mb2_f};
        int cum = 0;
        a.end[0] = 0;
        for (int s = 0; s < 13; ++s) {
            a.src[s] = d_in[srcIdx[s]];
            a.dst[s] = dsts[s];
            cum += in_sizes[srcIdx[s]];
            a.end[s + 1] = cum;
        }
        cvt_all_kernel<<<(cum + 255) / 256, 256, 0, stream>>>(a, flag, cum);
    }

    {
        TpArgs a;
        const float* srcs[5] = {iW1_f, iW2_f, mWmix_f, mW1_f, mW2_f};
        bf16* dsts[5] = {iW1T, iW2T, mWmixT, mW1T, mW2T};
        int Ks[5] = {F, F, F, 2 * F, F};
        int Nns[5] = {F, F3, 2 * F, F, F3};
        int cum = 0;
        a.end[0] = 0;
        for (int s = 0; s < 5; ++s) {
            a.src[s] = srcs[s];
            a.dst[s] = dsts[s];
            a.K[s] = Ks[s];
            a.Nn[s] = Nns[s];
            cum += NITER * Ks[s] * Nns[s];
            a.end[s + 1] = cum;
        }
        tpose_all_kernel<<<(cum + 255) / 256, 256, 0, stream>>>(a, cum);
    }
    {
        int total = NITER * F3 * KP;
        fwt_kernel<<<(total + 255) / 256, 256, 0, stream>>>(fW_f, fb_f, fWTf, total);
    }

    // CSR build (rank needed by geom)
    hipMemsetAsync(counts, 0, (size_t)N * 4, stream);
    count_kernel<<<(E + 255) / 256, 256, 0, stream>>>(idx_i, counts, E);
    scan_kernel<<<1, 1024, 0, stream>>>(counts, offs, N);
    hipMemsetAsync(counts, 0, (size_t)N * 4, stream);
    fill_kernel<<<(E + 255) / 256, 256, 0, stream>>>(idx_i, offs, counts, rank, E);

    geom_kernel<<<(E + 255) / 256, 256, 0, stream>>>(pos_f, idx_i, idx_j, rank,
                                                     phifc2, dir2, jj2, E);
    embed_kernel<<<(N * F + 255) / 256, 256, 0, stream>>>(z, emb_f, q, N);
    hipMemsetAsync(mua, 0, (size_t)N * F3 * 2, stream);

    bf16* muin = mua;
    bf16* muout = mub;
    for (int t = 0; t < NITER; ++t) {
        atom_x_mfma<<<(N + 31) / 32, 256, 0, stream>>>(q, iW1T + (size_t)t * F * F, ib1_f + t * F,
                                                       iW2T + (size_t)t * F3 * F, ib2_f + t * F3,
                                                       xbuf, N);
        edge_gather_pin<<<N, 128, 0, stream>>>(q, muin, xbuf, phifc2, dir2, jj2,
                                               fWTf + (size_t)t * F3 * KP, offs, muout, N);
        mix_mfma<<<(N + 15) / 16, 256, 0, stream>>>(q, muout, mWmixT + (size_t)t * 2 * F * F,
                                                    mW1T + (size_t)t * F * 2 * F, mb1_f + t * F,
                                                    mW2T + (size_t)t * F3 * F, mb2_f + t * F3, N);
        bf16* tm = muin; muin = muout; muout = tm;
    }

    int tot = N * (F + F3);
    out_kernel<<<(tot + 255) / 256, 256, 0, stream>>>(q, muin, d_out, N, flag);
}